// Round 5
// baseline (2146.060 us; speedup 1.0000x reference)
//
#include <hip/hip_runtime.h>
#include <hip/hip_bf16.h>

// VQ-VAE vector quantizer, MI355X — round 11.
// Rounds 7-10 post-mortem: every restructure of r6 (177us) regressed. r6 is
// the base. Two surgical changes: (1) single screen pass with BRANCHLESS
// candidate detection — bootstrap tiles 0-1 cache keys in 8 VGPRs (r8-
// verified), one barrier publishes the bootstrap threshold, tiles 2-15 pack
// the 8 per-step candidate tests into bit-masks (4 dwords, static indexing,
// loop fully unrolled); the rare branchy enqueue decodes masks AFTER the
// loop. No r7 spill (no key storage), no r8 in-loop branches (hot loop stays
// branchless so the compiler can pipeline loads across MFMAs). (2) prep
// kernels merged (swz float4-vectorized, c2 numerics untouched). Margin
// logic identical to r8 (passed): screen_true <= bootmin + 2*err <= bootmin
// + MARGIN_Q. Refine/epilogue/loss bit-identical to r6.
//
// d_out (float32): [0..16777215] z_q_st, [16777216] vq_loss, [+1..] indices.
// d_ws: [0,512K) cb_swz; [512K,+4K) c2; [528384,+16K) partials f64.

constexpr int D     = 256;
constexpr int NC    = 1024;
constexpr int NROWS = 65536;
constexpr int RPB   = 32;        // rows per block
constexpr int NBLK  = NROWS / RPB;   // 2048
constexpr int ZS    = 264;       // z_lds stride (floats)
constexpr int QCAP  = 512;       // block-wide candidate queue capacity
#define MARGIN_Q 3.8e-3f         // 3e-3 screen margin + 8e-4 bf16-store slack

typedef float accv4  __attribute__((ext_vector_type(4)));
typedef short short8 __attribute__((ext_vector_type(8)));

__device__ __forceinline__ short f2bf(float x) {
    __hip_bfloat16 h = __float2bfloat16(x);   // RNE (prep kernel only)
    return *reinterpret_cast<short*>(&h);
}
// pack truncated bf16(x) into low16, bf16(y) into high16 (2 VALU ops)
__device__ __forceinline__ unsigned packtrunc(float x, float y) {
    return (__float_as_uint(x) >> 16) | (__float_as_uint(y) & 0xffff0000u);
}

// numpy pairwise sum of x[0..127]^2 — 8-chain scheme (round-2 verified).
__device__ __forceinline__ float np_pairwise_sq128(const float* __restrict__ x) {
    float r[8];
    #pragma unroll
    for (int j = 0; j < 8; ++j) r[j] = __fmul_rn(x[j], x[j]);
    #pragma unroll
    for (int i = 8; i < 128; i += 8)
        #pragma unroll
        for (int j = 0; j < 8; ++j)
            r[j] = __fadd_rn(r[j], __fmul_rn(x[i + j], x[i + j]));
    float s01 = __fadd_rn(r[0], r[1]);
    float s23 = __fadd_rn(r[2], r[3]);
    float s45 = __fadd_rn(r[4], r[5]);
    float s67 = __fadd_rn(r[6], r[7]);
    return __fadd_rn(__fadd_rn(s01, s23), __fadd_rn(s45, s67));
}

// --- prep: swizzle (blocks 0..127, float4-vectorized) + c2 (blocks 128..131)
// swz: short8 element t = tile*512 + ks*64 + lane holds
//   cb[tile*16 + (lane&15)][ks*32 + (lane>>4)*8 + j],  j=0..7
__global__ void prep_kernel(const float* __restrict__ cb,
                            short* __restrict__ swz,
                            float* __restrict__ c2)
{
    int b = blockIdx.x;
    if (b < 128) {
        int t = b * 256 + threadIdx.x;   // 0..32767
        int lane = t & 63, ts = t >> 6;
        int ks = ts & 7, tile = ts >> 3;
        int code = tile * 16 + (lane & 15);
        int kb   = ks * 32 + (lane >> 4) * 8;
        const float* src = cb + (size_t)code * D + kb;
        float4 v0 = *(const float4*)(src);
        float4 v1 = *(const float4*)(src + 4);
        union { short s[8]; short8 v; } u;
        u.s[0] = f2bf(v0.x); u.s[1] = f2bf(v0.y);
        u.s[2] = f2bf(v0.z); u.s[3] = f2bf(v0.w);
        u.s[4] = f2bf(v1.x); u.s[5] = f2bf(v1.y);
        u.s[6] = f2bf(v1.z); u.s[7] = f2bf(v1.w);
        *((short8*)swz + t) = u.v;
    } else {
        int t = (b - 128) * 256 + threadIdx.x;
        if (t < NC) {
            const float* x = cb + (size_t)t * D;
            c2[t] = __fadd_rn(np_pairwise_sq128(x), np_pairwise_sq128(x + 128));
        }
    }
}

// --- main: branchless 1-pass screen + flat refine + epilogue ----------------
__global__ __launch_bounds__(256, 2) void vq_kernel(
    const float* __restrict__ z,
    const float* __restrict__ cb,
    const short* __restrict__ cb_swz,
    const float* __restrict__ c2g,
    float*       __restrict__ out_zq,
    float*       __restrict__ out_idx,
    double*      __restrict__ partials)
{
    __shared__ __align__(16) float z_lds[RPB][ZS];     // 33792 B
    __shared__ float a_row[RPB];
    __shared__ __align__(16) float scratchA[RPB][4];   // A_n tree; then best64
    __shared__ float c2_lds[NC];                        // 4096 B
    __shared__ int   rm_shared[RPB];                    // approx min; then winners
    __shared__ __align__(16) int queue[QCAP];           // 2048 B; then f64 scratch
    __shared__ int   qn;

    const int tid     = threadIdx.x;
    const int lane    = tid & 63;
    const int w       = tid >> 6;         // wave 0..3
    const int rowBase = blockIdx.x * RPB;

    // ---- phase 1: stage z (fp32), c2, init ----
    #pragma unroll
    for (int j = 0; j < 8; ++j) {
        int l = tid + 256 * j;
        int row = l >> 6, q = l & 63;
        float4 v = *(const float4*)(z + (size_t)(rowBase + row) * D + q * 4);
        *(float4*)&z_lds[row][q * 4] = v;
    }
    #pragma unroll
    for (int j = 0; j < 4; ++j) c2_lds[tid + 256 * j] = c2g[tid + 256 * j];
    if (tid < RPB) rm_shared[tid] = 0x7f800000;   // +inf
    if (tid == 0)  qn = 0;
    __syncthreads();

    // ---- phase 2: A_n (numpy pairwise, round-2-exact tree), 4 threads/row ----
    if (tid < RPB * 4) {
        int row = tid >> 2, q = tid & 3;
        int h = (q >> 1) * 128, p = (q & 1) * 4;
        const float* x = &z_lds[row][0];
        float r0 = __fmul_rn(x[h+p+0], x[h+p+0]);
        float r1 = __fmul_rn(x[h+p+1], x[h+p+1]);
        float r2 = __fmul_rn(x[h+p+2], x[h+p+2]);
        float r3 = __fmul_rn(x[h+p+3], x[h+p+3]);
        #pragma unroll
        for (int i = 8; i < 128; i += 8) {
            r0 = __fadd_rn(r0, __fmul_rn(x[h+i+p+0], x[h+i+p+0]));
            r1 = __fadd_rn(r1, __fmul_rn(x[h+i+p+1], x[h+i+p+1]));
            r2 = __fadd_rn(r2, __fmul_rn(x[h+i+p+2], x[h+i+p+2]));
            r3 = __fadd_rn(r3, __fmul_rn(x[h+i+p+3], x[h+i+p+3]));
        }
        scratchA[row][q] = __fadd_rn(__fadd_rn(r0, r1), __fadd_rn(r2, r3));
    }
    __syncthreads();
    if (tid < RPB) {
        float half0 = __fadd_rn(scratchA[tid][0], scratchA[tid][1]);
        float half1 = __fadd_rn(scratchA[tid][2], scratchA[tid][3]);
        a_row[tid]  = __fadd_rn(half0, half1);
    }
    __syncthreads();

    // ---- phase 3: A-fragments from GLOBAL z (truncated bf16, no LDS) ----
    // lane L, row-tile rt, k-slice ks: rows rt*16+(L&15), dims ks*32+(L>>4)*8..+7
    short8 afrag[2][8];
    #pragma unroll
    for (int rt = 0; rt < 2; ++rt)
        #pragma unroll
        for (int ks = 0; ks < 8; ++ks) {
            const float* src = z + (size_t)(rowBase + rt * 16 + (lane & 15)) * D
                                 + ks * 32 + (lane >> 4) * 8;
            float4 v0 = *(const float4*)(src);
            float4 v1 = *(const float4*)(src + 4);
            union { unsigned u[4]; short8 v; } pk;
            pk.u[0] = packtrunc(v0.x, v0.y);
            pk.u[1] = packtrunc(v0.z, v0.w);
            pk.u[2] = packtrunc(v1.x, v1.y);
            pk.u[3] = packtrunc(v1.z, v1.w);
            afrag[rt][ks] = pk.v;
        }
    float a_reg[2][4];
    #pragma unroll
    for (int rt = 0; rt < 2; ++rt)
        #pragma unroll
        for (int i = 0; i < 4; ++i)
            a_reg[rt][i] = a_row[rt * 16 + (lane >> 4) * 4 + i];

    // ---- phase 4: SINGLE-pass screen ----
    // key(row,code) = a - m,  m = 2*(z.c)_bf16 - ||c||^2.
    const short8* bbase = (const short8*)cb_swz + lane;

    // -- bootstrap: tiles 0..1 (codes 0..127 across 4 waves), keys in 8 VGPRs --
    float runmin[2][4];
    #pragma unroll
    for (int rt = 0; rt < 2; ++rt)
        #pragma unroll
        for (int i = 0; i < 4; ++i) runmin[rt][i] = 3.4e38f;

    unsigned kpk[2][2][2];
    #pragma unroll
    for (int t = 0; t < 2; ++t) {
        const int tile = w + 4 * t;
        short8 bf[8];
        #pragma unroll
        for (int ks = 0; ks < 8; ++ks)
            bf[ks] = bbase[(size_t)tile * 512 + ks * 64];
        accv4 acc[2];
        #pragma unroll
        for (int rt = 0; rt < 2; ++rt) acc[rt] = (accv4){0.f, 0.f, 0.f, 0.f};
        #pragma unroll
        for (int ks = 0; ks < 8; ++ks) {
            #pragma unroll
            for (int rt = 0; rt < 2; ++rt)
                acc[rt] = __builtin_amdgcn_mfma_f32_16x16x32_bf16(
                    afrag[rt][ks], bf[ks], acc[rt], 0, 0, 0);
        }
        const float c2v = c2_lds[tile * 16 + (lane & 15)];
        #pragma unroll
        for (int rt = 0; rt < 2; ++rt) {
            float m0 = fmaf(2.0f, acc[rt][0], -c2v);
            float m1 = fmaf(2.0f, acc[rt][1], -c2v);
            float m2 = fmaf(2.0f, acc[rt][2], -c2v);
            float m3 = fmaf(2.0f, acc[rt][3], -c2v);
            kpk[t][rt][0] = packtrunc(m0, m1);
            kpk[t][rt][1] = packtrunc(m2, m3);
            runmin[rt][0] = fminf(runmin[rt][0], a_reg[rt][0] - m0);
            runmin[rt][1] = fminf(runmin[rt][1], a_reg[rt][1] - m1);
            runmin[rt][2] = fminf(runmin[rt][2], a_reg[rt][2] - m2);
            runmin[rt][3] = fminf(runmin[rt][3], a_reg[rt][3] - m3);
        }
    }

    // publish bootstrap mins (all waves), one barrier for the threshold
    #pragma unroll
    for (int rt = 0; rt < 2; ++rt)
        #pragma unroll
        for (int i = 0; i < 4; ++i) {
            float m = runmin[rt][i];
            m = fminf(m, __shfl_xor(m, 1));
            m = fminf(m, __shfl_xor(m, 2));
            m = fminf(m, __shfl_xor(m, 4));
            m = fminf(m, __shfl_xor(m, 8));
            if ((lane & 15) == 0) {
                int row = rt * 16 + (lane >> 4) * 4 + i;
                atomicMin(&rm_shared[row], __float_as_int(m));
            }
        }
    __syncthreads();

    float mthr[2][4];      // candidate iff m >= mthr  (<=> key <= min + margin)
    #pragma unroll
    for (int rt = 0; rt < 2; ++rt)
        #pragma unroll
        for (int i = 0; i < 4; ++i) {
            int row = rt * 16 + (lane >> 4) * 4 + i;
            mthr[rt][i] = a_reg[rt][i]
                        - (__int_as_float(rm_shared[row]) + MARGIN_Q);
        }

    // scan the 2-step bootstrap cache (branchy, rare-taken)
    #pragma unroll
    for (int t = 0; t < 2; ++t) {
        const int code = (w + 4 * t) * 16 + (lane & 15);
        #pragma unroll
        for (int rt = 0; rt < 2; ++rt)
            #pragma unroll
            for (int pr = 0; pr < 2; ++pr) {
                unsigned pk = kpk[t][rt][pr];
                float mlo = __uint_as_float(pk << 16);
                float mhi = __uint_as_float(pk & 0xffff0000u);
                if (mlo >= mthr[rt][2 * pr]) {
                    int row  = rt * 16 + (lane >> 4) * 4 + 2 * pr;
                    int slot = atomicAdd(&qn, 1);
                    if (slot < QCAP) queue[slot] = (row << 10) | code;
                }
                if (mhi >= mthr[rt][2 * pr + 1]) {
                    int row  = rt * 16 + (lane >> 4) * 4 + 2 * pr + 1;
                    int slot = atomicAdd(&qn, 1);
                    if (slot < QCAP) queue[slot] = (row << 10) | code;
                }
            }
    }

    // -- main: tiles 2..15, BRANCHLESS — pack candidate tests into bit-masks --
    // mw[(t-2)>>2] bits [((t-2)&3)*8 + rt*4 + i]; fully unrolled (static idx).
    unsigned mw[4] = {0u, 0u, 0u, 0u};
    #pragma unroll
    for (int t = 2; t < 16; ++t) {
        const int tile = w + 4 * t;
        short8 bf[8];
        #pragma unroll
        for (int ks = 0; ks < 8; ++ks)
            bf[ks] = bbase[(size_t)tile * 512 + ks * 64];
        accv4 acc[2];
        #pragma unroll
        for (int rt = 0; rt < 2; ++rt) acc[rt] = (accv4){0.f, 0.f, 0.f, 0.f};
        #pragma unroll
        for (int ks = 0; ks < 8; ++ks) {
            #pragma unroll
            for (int rt = 0; rt < 2; ++rt)
                acc[rt] = __builtin_amdgcn_mfma_f32_16x16x32_bf16(
                    afrag[rt][ks], bf[ks], acc[rt], 0, 0, 0);
        }
        const float c2v = c2_lds[tile * 16 + (lane & 15)];
        unsigned bits = 0u;
        #pragma unroll
        for (int rt = 0; rt < 2; ++rt) {
            #pragma unroll
            for (int i = 0; i < 4; ++i) {
                float m = fmaf(2.0f, acc[rt][i], -c2v);
                bits |= (m >= mthr[rt][i]) ? (1u << (rt * 4 + i)) : 0u;
            }
        }
        mw[(t - 2) >> 2] |= bits << (((t - 2) & 3) * 8);
    }

    // -- post-loop: decode masks, enqueue (branchy, rare-taken) --
    #pragma unroll
    for (int t = 2; t < 16; ++t) {
        unsigned byte = (mw[(t - 2) >> 2] >> (((t - 2) & 3) * 8)) & 0xffu;
        if (byte) {
            const int code = (w + 4 * t) * 16 + (lane & 15);
            #pragma unroll
            for (int rt = 0; rt < 2; ++rt)
                #pragma unroll
                for (int i = 0; i < 4; ++i)
                    if (byte & (1u << (rt * 4 + i))) {
                        int row  = rt * 16 + (lane >> 4) * 4 + i;
                        int slot = atomicAdd(&qn, 1);
                        if (slot < QCAP) queue[slot] = (row << 10) | code;
                    }
        }
    }

    // ---- phase 5: exact refinement (bit-identical to round-2 keys) ----
    unsigned long long* best64 = (unsigned long long*)&scratchA[0][0];
    if (tid < RPB) best64[tid] = ~0ull;
    __syncthreads();
    int total = qn;
    if (total <= QCAP) {
        for (int t = tid; t < total; t += 256) {
            int e = queue[t];
            int row = e >> 10, code = e & 1023;
            const float4* cp = (const float4*)(cb + (size_t)code * D);
            const float*  zr = &z_lds[row][0];
            float acc = 0.0f;
            #pragma unroll 8
            for (int d4 = 0; d4 < 64; ++d4) {
                float4 cv = cp[d4];
                acc = fmaf(zr[d4 * 4 + 0], cv.x, acc);
                acc = fmaf(zr[d4 * 4 + 1], cv.y, acc);
                acc = fmaf(zr[d4 * 4 + 2], cv.z, acc);
                acc = fmaf(zr[d4 * 4 + 3], cv.w, acc);
            }
            float key = __fsub_rn(__fadd_rn(a_row[row], c2_lds[code]), 2.0f * acc);
            unsigned long long pk =
                ((unsigned long long)__float_as_uint(key) << 32) | (unsigned)code;
            atomicMin(&best64[row], pk);
        }
    } else {
        for (int r = 0; r < RPB; ++r) {
            for (int c = tid; c < NC; c += 256) {
                const float4* cp = (const float4*)(cb + (size_t)c * D);
                const float*  zr = &z_lds[r][0];
                float acc = 0.0f;
                #pragma unroll 8
                for (int d4 = 0; d4 < 64; ++d4) {
                    float4 cv = cp[d4];
                    acc = fmaf(zr[d4 * 4 + 0], cv.x, acc);
                    acc = fmaf(zr[d4 * 4 + 1], cv.y, acc);
                    acc = fmaf(zr[d4 * 4 + 2], cv.z, acc);
                    acc = fmaf(zr[d4 * 4 + 3], cv.w, acc);
                }
                float key = __fsub_rn(__fadd_rn(a_row[r], c2_lds[c]), 2.0f * acc);
                unsigned long long pk =
                    ((unsigned long long)__float_as_uint(key) << 32) | (unsigned)c;
                atomicMin(&best64[r], pk);
            }
        }
    }
    __syncthreads();

    // ---- phase 6: winners ----
    int* winner = rm_shared;   // reuse
    if (tid < RPB) {
        unsigned long long b = best64[tid];
        int wdx = (b == ~0ull) ? 0 : (int)(b & 0xffffffffu);
        winner[tid] = wdx;
        out_idx[rowBase + tid] = (float)wdx;
    }
    __syncthreads();

    // ---- phase 7: vectorized epilogue (float4 path, wave-uniform row) ----
    double lacc = 0.0;
    #pragma unroll
    for (int j = 0; j < 8; ++j) {
        int idx = tid + 256 * j;      // 0..2047
        int row = idx >> 6;           // wave-uniform
        int q4  = idx & 63;
        int wd  = winner[row];
        float4 cv = *(const float4*)(cb + (size_t)wd * D + q4 * 4);
        float4 zv = *(const float4*)&z_lds[row][q4 * 4];
        float4 o;
        o.x = __fadd_rn(zv.x, __fsub_rn(cv.x, zv.x));
        o.y = __fadd_rn(zv.y, __fsub_rn(cv.y, zv.y));
        o.z = __fadd_rn(zv.z, __fsub_rn(cv.z, zv.z));
        o.w = __fadd_rn(zv.w, __fsub_rn(cv.w, zv.w));
        *(float4*)(out_zq + (size_t)(rowBase + row) * D + q4 * 4) = o;
        double d0 = (double)zv.x - (double)cv.x;
        double d1 = (double)zv.y - (double)cv.y;
        double d2 = (double)zv.z - (double)cv.z;
        double d3 = (double)zv.w - (double)cv.w;
        lacc += d0 * d0 + d1 * d1 + d2 * d2 + d3 * d3;
    }
    __syncthreads();
    double* dred = (double*)&queue[0];   // 512 ints = 256 doubles
    dred[tid] = lacc;
    __syncthreads();
    for (int s = 128; s > 0; s >>= 1) {
        if (tid < s) dred[tid] += dred[tid + s];
        __syncthreads();
    }
    if (tid == 0) partials[blockIdx.x] = dred[0];
}

// --- final loss reduction ---------------------------------------------------
__global__ void loss_kernel(const double* __restrict__ partials,
                            float* __restrict__ out_loss)
{
    __shared__ double sm[256];
    int tid = threadIdx.x;
    double s = 0.0;
    for (int i = tid; i < NBLK; i += 256) s += partials[i];
    sm[tid] = s;
    __syncthreads();
    for (int k = 128; k > 0; k >>= 1) {
        if (tid < k) sm[tid] += sm[tid + k];
        __syncthreads();
    }
    if (tid == 0)
        out_loss[0] = (float)(1.25 * sm[0] / (double)((size_t)NROWS * D));
}

extern "C" void kernel_launch(void* const* d_in, const int* in_sizes, int n_in,
                              void* d_out, int out_size, void* d_ws, size_t ws_size,
                              hipStream_t stream)
{
    const float* z  = (const float*)d_in[0];   // [65536, 256]
    const float* cb = (const float*)d_in[1];   // [1024, 256]

    float* out      = (float*)d_out;
    float* out_zq   = out;
    float* out_loss = out + (size_t)NROWS * D;
    float* out_idx  = out_loss + 1;

    char*   ws       = (char*)d_ws;
    short*  cb_swz   = (short*)ws;                       // 512 KB
    float*  c2       = (float*)(ws + 524288);            // 4 KB
    double* partials = (double*)(ws + 528384);           // 16 KB

    prep_kernel<<<132, 256, 0, stream>>>(cb, cb_swz, c2);
    vq_kernel<<<NBLK, 256, 0, stream>>>(z, cb, cb_swz, c2,
                                        out_zq, out_idx, partials);
    loss_kernel<<<1, 256, 0, stream>>>(partials, out_loss);
}

// Round 6
// 330.750 us; speedup vs baseline: 6.4885x; 6.4885x over previous
//
#include <hip/hip_runtime.h>
#include <hip/hip_bf16.h>

// VQ-VAE vector quantizer, MI355X — round 12.
// Round-11 post-mortem: 2130us regression was ONE constant — QCAP=512 with
// the bootstrap-128 threshold (expected qn ~400-700/block by order stats)
// => queue overflow => full-scan fallback in ~every block (196us absolute
// VALU, 4.6x bank conflicts, MFMA absolute time unchanged). The branchless
// screen itself ran fine. Round 12 = round 11 with QCAP=2048 (8KB LDS, 3x
// expected qn; refine at qn~600 is ~3us). This is the clean A/B of the
// branchless single-pass screen vs r6's 2-pass (177us).
//
// d_out (float32): [0..16777215] z_q_st, [16777216] vq_loss, [+1..] indices.
// d_ws: [0,512K) cb_swz; [512K,+4K) c2; [528384,+16K) partials f64.

constexpr int D     = 256;
constexpr int NC    = 1024;
constexpr int NROWS = 65536;
constexpr int RPB   = 32;        // rows per block
constexpr int NBLK  = NROWS / RPB;   // 2048
constexpr int ZS    = 264;       // z_lds stride (floats)
constexpr int QCAP  = 2048;      // candidate queue capacity (3x expected qn)
#define MARGIN_Q 3.8e-3f         // 3e-3 screen margin + 8e-4 bf16-store slack

typedef float accv4  __attribute__((ext_vector_type(4)));
typedef short short8 __attribute__((ext_vector_type(8)));

__device__ __forceinline__ short f2bf(float x) {
    __hip_bfloat16 h = __float2bfloat16(x);   // RNE (prep kernel only)
    return *reinterpret_cast<short*>(&h);
}
// pack truncated bf16(x) into low16, bf16(y) into high16 (2 VALU ops)
__device__ __forceinline__ unsigned packtrunc(float x, float y) {
    return (__float_as_uint(x) >> 16) | (__float_as_uint(y) & 0xffff0000u);
}

// numpy pairwise sum of x[0..127]^2 — 8-chain scheme (round-2 verified).
__device__ __forceinline__ float np_pairwise_sq128(const float* __restrict__ x) {
    float r[8];
    #pragma unroll
    for (int j = 0; j < 8; ++j) r[j] = __fmul_rn(x[j], x[j]);
    #pragma unroll
    for (int i = 8; i < 128; i += 8)
        #pragma unroll
        for (int j = 0; j < 8; ++j)
            r[j] = __fadd_rn(r[j], __fmul_rn(x[i + j], x[i + j]));
    float s01 = __fadd_rn(r[0], r[1]);
    float s23 = __fadd_rn(r[2], r[3]);
    float s45 = __fadd_rn(r[4], r[5]);
    float s67 = __fadd_rn(r[6], r[7]);
    return __fadd_rn(__fadd_rn(s01, s23), __fadd_rn(s45, s67));
}

// --- prep: swizzle (blocks 0..127, float4-vectorized) + c2 (blocks 128..131)
// swz: short8 element t = tile*512 + ks*64 + lane holds
//   cb[tile*16 + (lane&15)][ks*32 + (lane>>4)*8 + j],  j=0..7
__global__ void prep_kernel(const float* __restrict__ cb,
                            short* __restrict__ swz,
                            float* __restrict__ c2)
{
    int b = blockIdx.x;
    if (b < 128) {
        int t = b * 256 + threadIdx.x;   // 0..32767
        int lane = t & 63, ts = t >> 6;
        int ks = ts & 7, tile = ts >> 3;
        int code = tile * 16 + (lane & 15);
        int kb   = ks * 32 + (lane >> 4) * 8;
        const float* src = cb + (size_t)code * D + kb;
        float4 v0 = *(const float4*)(src);
        float4 v1 = *(const float4*)(src + 4);
        union { short s[8]; short8 v; } u;
        u.s[0] = f2bf(v0.x); u.s[1] = f2bf(v0.y);
        u.s[2] = f2bf(v0.z); u.s[3] = f2bf(v0.w);
        u.s[4] = f2bf(v1.x); u.s[5] = f2bf(v1.y);
        u.s[6] = f2bf(v1.z); u.s[7] = f2bf(v1.w);
        *((short8*)swz + t) = u.v;
    } else {
        int t = (b - 128) * 256 + threadIdx.x;
        if (t < NC) {
            const float* x = cb + (size_t)t * D;
            c2[t] = __fadd_rn(np_pairwise_sq128(x), np_pairwise_sq128(x + 128));
        }
    }
}

// --- main: branchless 1-pass screen + flat refine + epilogue ----------------
__global__ __launch_bounds__(256, 2) void vq_kernel(
    const float* __restrict__ z,
    const float* __restrict__ cb,
    const short* __restrict__ cb_swz,
    const float* __restrict__ c2g,
    float*       __restrict__ out_zq,
    float*       __restrict__ out_idx,
    double*      __restrict__ partials)
{
    __shared__ __align__(16) float z_lds[RPB][ZS];     // 33792 B
    __shared__ float a_row[RPB];
    __shared__ __align__(16) float scratchA[RPB][4];   // A_n tree; then best64
    __shared__ float c2_lds[NC];                        // 4096 B
    __shared__ int   rm_shared[RPB];                    // approx min; then winners
    __shared__ __align__(16) int queue[QCAP];           // 8192 B; then f64 scratch
    __shared__ int   qn;

    const int tid     = threadIdx.x;
    const int lane    = tid & 63;
    const int w       = tid >> 6;         // wave 0..3
    const int rowBase = blockIdx.x * RPB;

    // ---- phase 1: stage z (fp32), c2, init ----
    #pragma unroll
    for (int j = 0; j < 8; ++j) {
        int l = tid + 256 * j;
        int row = l >> 6, q = l & 63;
        float4 v = *(const float4*)(z + (size_t)(rowBase + row) * D + q * 4);
        *(float4*)&z_lds[row][q * 4] = v;
    }
    #pragma unroll
    for (int j = 0; j < 4; ++j) c2_lds[tid + 256 * j] = c2g[tid + 256 * j];
    if (tid < RPB) rm_shared[tid] = 0x7f800000;   // +inf
    if (tid == 0)  qn = 0;
    __syncthreads();

    // ---- phase 2: A_n (numpy pairwise, round-2-exact tree), 4 threads/row ----
    if (tid < RPB * 4) {
        int row = tid >> 2, q = tid & 3;
        int h = (q >> 1) * 128, p = (q & 1) * 4;
        const float* x = &z_lds[row][0];
        float r0 = __fmul_rn(x[h+p+0], x[h+p+0]);
        float r1 = __fmul_rn(x[h+p+1], x[h+p+1]);
        float r2 = __fmul_rn(x[h+p+2], x[h+p+2]);
        float r3 = __fmul_rn(x[h+p+3], x[h+p+3]);
        #pragma unroll
        for (int i = 8; i < 128; i += 8) {
            r0 = __fadd_rn(r0, __fmul_rn(x[h+i+p+0], x[h+i+p+0]));
            r1 = __fadd_rn(r1, __fmul_rn(x[h+i+p+1], x[h+i+p+1]));
            r2 = __fadd_rn(r2, __fmul_rn(x[h+i+p+2], x[h+i+p+2]));
            r3 = __fadd_rn(r3, __fmul_rn(x[h+i+p+3], x[h+i+p+3]));
        }
        scratchA[row][q] = __fadd_rn(__fadd_rn(r0, r1), __fadd_rn(r2, r3));
    }
    __syncthreads();
    if (tid < RPB) {
        float half0 = __fadd_rn(scratchA[tid][0], scratchA[tid][1]);
        float half1 = __fadd_rn(scratchA[tid][2], scratchA[tid][3]);
        a_row[tid]  = __fadd_rn(half0, half1);
    }
    __syncthreads();

    // ---- phase 3: A-fragments from GLOBAL z (truncated bf16, no LDS) ----
    // lane L, row-tile rt, k-slice ks: rows rt*16+(L&15), dims ks*32+(L>>4)*8..+7
    short8 afrag[2][8];
    #pragma unroll
    for (int rt = 0; rt < 2; ++rt)
        #pragma unroll
        for (int ks = 0; ks < 8; ++ks) {
            const float* src = z + (size_t)(rowBase + rt * 16 + (lane & 15)) * D
                                 + ks * 32 + (lane >> 4) * 8;
            float4 v0 = *(const float4*)(src);
            float4 v1 = *(const float4*)(src + 4);
            union { unsigned u[4]; short8 v; } pk;
            pk.u[0] = packtrunc(v0.x, v0.y);
            pk.u[1] = packtrunc(v0.z, v0.w);
            pk.u[2] = packtrunc(v1.x, v1.y);
            pk.u[3] = packtrunc(v1.z, v1.w);
            afrag[rt][ks] = pk.v;
        }
    float a_reg[2][4];
    #pragma unroll
    for (int rt = 0; rt < 2; ++rt)
        #pragma unroll
        for (int i = 0; i < 4; ++i)
            a_reg[rt][i] = a_row[rt * 16 + (lane >> 4) * 4 + i];

    // ---- phase 4: SINGLE-pass screen ----
    // key(row,code) = a - m,  m = 2*(z.c)_bf16 - ||c||^2.
    const short8* bbase = (const short8*)cb_swz + lane;

    // -- bootstrap: tiles 0..1 (codes 0..127 across 4 waves), keys in 8 VGPRs --
    float runmin[2][4];
    #pragma unroll
    for (int rt = 0; rt < 2; ++rt)
        #pragma unroll
        for (int i = 0; i < 4; ++i) runmin[rt][i] = 3.4e38f;

    unsigned kpk[2][2][2];
    #pragma unroll
    for (int t = 0; t < 2; ++t) {
        const int tile = w + 4 * t;
        short8 bf[8];
        #pragma unroll
        for (int ks = 0; ks < 8; ++ks)
            bf[ks] = bbase[(size_t)tile * 512 + ks * 64];
        accv4 acc[2];
        #pragma unroll
        for (int rt = 0; rt < 2; ++rt) acc[rt] = (accv4){0.f, 0.f, 0.f, 0.f};
        #pragma unroll
        for (int ks = 0; ks < 8; ++ks) {
            #pragma unroll
            for (int rt = 0; rt < 2; ++rt)
                acc[rt] = __builtin_amdgcn_mfma_f32_16x16x32_bf16(
                    afrag[rt][ks], bf[ks], acc[rt], 0, 0, 0);
        }
        const float c2v = c2_lds[tile * 16 + (lane & 15)];
        #pragma unroll
        for (int rt = 0; rt < 2; ++rt) {
            float m0 = fmaf(2.0f, acc[rt][0], -c2v);
            float m1 = fmaf(2.0f, acc[rt][1], -c2v);
            float m2 = fmaf(2.0f, acc[rt][2], -c2v);
            float m3 = fmaf(2.0f, acc[rt][3], -c2v);
            kpk[t][rt][0] = packtrunc(m0, m1);
            kpk[t][rt][1] = packtrunc(m2, m3);
            runmin[rt][0] = fminf(runmin[rt][0], a_reg[rt][0] - m0);
            runmin[rt][1] = fminf(runmin[rt][1], a_reg[rt][1] - m1);
            runmin[rt][2] = fminf(runmin[rt][2], a_reg[rt][2] - m2);
            runmin[rt][3] = fminf(runmin[rt][3], a_reg[rt][3] - m3);
        }
    }

    // publish bootstrap mins (all waves), one barrier for the threshold
    #pragma unroll
    for (int rt = 0; rt < 2; ++rt)
        #pragma unroll
        for (int i = 0; i < 4; ++i) {
            float m = runmin[rt][i];
            m = fminf(m, __shfl_xor(m, 1));
            m = fminf(m, __shfl_xor(m, 2));
            m = fminf(m, __shfl_xor(m, 4));
            m = fminf(m, __shfl_xor(m, 8));
            if ((lane & 15) == 0) {
                int row = rt * 16 + (lane >> 4) * 4 + i;
                atomicMin(&rm_shared[row], __float_as_int(m));
            }
        }
    __syncthreads();

    float mthr[2][4];      // candidate iff m >= mthr  (<=> key <= min + margin)
    #pragma unroll
    for (int rt = 0; rt < 2; ++rt)
        #pragma unroll
        for (int i = 0; i < 4; ++i) {
            int row = rt * 16 + (lane >> 4) * 4 + i;
            mthr[rt][i] = a_reg[rt][i]
                        - (__int_as_float(rm_shared[row]) + MARGIN_Q);
        }

    // scan the 2-step bootstrap cache (branchy, rare-taken)
    #pragma unroll
    for (int t = 0; t < 2; ++t) {
        const int code = (w + 4 * t) * 16 + (lane & 15);
        #pragma unroll
        for (int rt = 0; rt < 2; ++rt)
            #pragma unroll
            for (int pr = 0; pr < 2; ++pr) {
                unsigned pk = kpk[t][rt][pr];
                float mlo = __uint_as_float(pk << 16);
                float mhi = __uint_as_float(pk & 0xffff0000u);
                if (mlo >= mthr[rt][2 * pr]) {
                    int row  = rt * 16 + (lane >> 4) * 4 + 2 * pr;
                    int slot = atomicAdd(&qn, 1);
                    if (slot < QCAP) queue[slot] = (row << 10) | code;
                }
                if (mhi >= mthr[rt][2 * pr + 1]) {
                    int row  = rt * 16 + (lane >> 4) * 4 + 2 * pr + 1;
                    int slot = atomicAdd(&qn, 1);
                    if (slot < QCAP) queue[slot] = (row << 10) | code;
                }
            }
    }

    // -- main: tiles 2..15, BRANCHLESS — pack candidate tests into bit-masks --
    // mw[(t-2)>>2] bits [((t-2)&3)*8 + rt*4 + i]; fully unrolled (static idx).
    unsigned mw[4] = {0u, 0u, 0u, 0u};
    #pragma unroll
    for (int t = 2; t < 16; ++t) {
        const int tile = w + 4 * t;
        short8 bf[8];
        #pragma unroll
        for (int ks = 0; ks < 8; ++ks)
            bf[ks] = bbase[(size_t)tile * 512 + ks * 64];
        accv4 acc[2];
        #pragma unroll
        for (int rt = 0; rt < 2; ++rt) acc[rt] = (accv4){0.f, 0.f, 0.f, 0.f};
        #pragma unroll
        for (int ks = 0; ks < 8; ++ks) {
            #pragma unroll
            for (int rt = 0; rt < 2; ++rt)
                acc[rt] = __builtin_amdgcn_mfma_f32_16x16x32_bf16(
                    afrag[rt][ks], bf[ks], acc[rt], 0, 0, 0);
        }
        const float c2v = c2_lds[tile * 16 + (lane & 15)];
        unsigned bits = 0u;
        #pragma unroll
        for (int rt = 0; rt < 2; ++rt) {
            #pragma unroll
            for (int i = 0; i < 4; ++i) {
                float m = fmaf(2.0f, acc[rt][i], -c2v);
                bits |= (m >= mthr[rt][i]) ? (1u << (rt * 4 + i)) : 0u;
            }
        }
        mw[(t - 2) >> 2] |= bits << (((t - 2) & 3) * 8);
    }

    // -- post-loop: decode masks, enqueue (branchy, rare-taken) --
    #pragma unroll
    for (int t = 2; t < 16; ++t) {
        unsigned byte = (mw[(t - 2) >> 2] >> (((t - 2) & 3) * 8)) & 0xffu;
        if (byte) {
            const int code = (w + 4 * t) * 16 + (lane & 15);
            #pragma unroll
            for (int rt = 0; rt < 2; ++rt)
                #pragma unroll
                for (int i = 0; i < 4; ++i)
                    if (byte & (1u << (rt * 4 + i))) {
                        int row  = rt * 16 + (lane >> 4) * 4 + i;
                        int slot = atomicAdd(&qn, 1);
                        if (slot < QCAP) queue[slot] = (row << 10) | code;
                    }
        }
    }

    // ---- phase 5: exact refinement (bit-identical to round-2 keys) ----
    unsigned long long* best64 = (unsigned long long*)&scratchA[0][0];
    if (tid < RPB) best64[tid] = ~0ull;
    __syncthreads();
    int total = qn;
    if (total <= QCAP) {
        for (int t = tid; t < total; t += 256) {
            int e = queue[t];
            int row = e >> 10, code = e & 1023;
            const float4* cp = (const float4*)(cb + (size_t)code * D);
            const float*  zr = &z_lds[row][0];
            float acc = 0.0f;
            #pragma unroll 8
            for (int d4 = 0; d4 < 64; ++d4) {
                float4 cv = cp[d4];
                acc = fmaf(zr[d4 * 4 + 0], cv.x, acc);
                acc = fmaf(zr[d4 * 4 + 1], cv.y, acc);
                acc = fmaf(zr[d4 * 4 + 2], cv.z, acc);
                acc = fmaf(zr[d4 * 4 + 3], cv.w, acc);
            }
            float key = __fsub_rn(__fadd_rn(a_row[row], c2_lds[code]), 2.0f * acc);
            unsigned long long pk =
                ((unsigned long long)__float_as_uint(key) << 32) | (unsigned)code;
            atomicMin(&best64[row], pk);
        }
    } else {
        for (int r = 0; r < RPB; ++r) {
            for (int c = tid; c < NC; c += 256) {
                const float4* cp = (const float4*)(cb + (size_t)c * D);
                const float*  zr = &z_lds[r][0];
                float acc = 0.0f;
                #pragma unroll 8
                for (int d4 = 0; d4 < 64; ++d4) {
                    float4 cv = cp[d4];
                    acc = fmaf(zr[d4 * 4 + 0], cv.x, acc);
                    acc = fmaf(zr[d4 * 4 + 1], cv.y, acc);
                    acc = fmaf(zr[d4 * 4 + 2], cv.z, acc);
                    acc = fmaf(zr[d4 * 4 + 3], cv.w, acc);
                }
                float key = __fsub_rn(__fadd_rn(a_row[r], c2_lds[c]), 2.0f * acc);
                unsigned long long pk =
                    ((unsigned long long)__float_as_uint(key) << 32) | (unsigned)c;
                atomicMin(&best64[r], pk);
            }
        }
    }
    __syncthreads();

    // ---- phase 6: winners ----
    int* winner = rm_shared;   // reuse
    if (tid < RPB) {
        unsigned long long b = best64[tid];
        int wdx = (b == ~0ull) ? 0 : (int)(b & 0xffffffffu);
        winner[tid] = wdx;
        out_idx[rowBase + tid] = (float)wdx;
    }
    __syncthreads();

    // ---- phase 7: vectorized epilogue (float4 path, wave-uniform row) ----
    double lacc = 0.0;
    #pragma unroll
    for (int j = 0; j < 8; ++j) {
        int idx = tid + 256 * j;      // 0..2047
        int row = idx >> 6;           // wave-uniform
        int q4  = idx & 63;
        int wd  = winner[row];
        float4 cv = *(const float4*)(cb + (size_t)wd * D + q4 * 4);
        float4 zv = *(const float4*)&z_lds[row][q4 * 4];
        float4 o;
        o.x = __fadd_rn(zv.x, __fsub_rn(cv.x, zv.x));
        o.y = __fadd_rn(zv.y, __fsub_rn(cv.y, zv.y));
        o.z = __fadd_rn(zv.z, __fsub_rn(cv.z, zv.z));
        o.w = __fadd_rn(zv.w, __fsub_rn(cv.w, zv.w));
        *(float4*)(out_zq + (size_t)(rowBase + row) * D + q4 * 4) = o;
        double d0 = (double)zv.x - (double)cv.x;
        double d1 = (double)zv.y - (double)cv.y;
        double d2 = (double)zv.z - (double)cv.z;
        double d3 = (double)zv.w - (double)cv.w;
        lacc += d0 * d0 + d1 * d1 + d2 * d2 + d3 * d3;
    }
    __syncthreads();
    double* dred = (double*)&queue[0];   // 256 doubles = 2048 B, fits in queue
    dred[tid] = lacc;
    __syncthreads();
    for (int s = 128; s > 0; s >>= 1) {
        if (tid < s) dred[tid] += dred[tid + s];
        __syncthreads();
    }
    if (tid == 0) partials[blockIdx.x] = dred[0];
}

// --- final loss reduction ---------------------------------------------------
__global__ void loss_kernel(const double* __restrict__ partials,
                            float* __restrict__ out_loss)
{
    __shared__ double sm[256];
    int tid = threadIdx.x;
    double s = 0.0;
    for (int i = tid; i < NBLK; i += 256) s += partials[i];
    sm[tid] = s;
    __syncthreads();
    for (int k = 128; k > 0; k >>= 1) {
        if (tid < k) sm[tid] += sm[tid + k];
        __syncthreads();
    }
    if (tid == 0)
        out_loss[0] = (float)(1.25 * sm[0] / (double)((size_t)NROWS * D));
}

extern "C" void kernel_launch(void* const* d_in, const int* in_sizes, int n_in,
                              void* d_out, int out_size, void* d_ws, size_t ws_size,
                              hipStream_t stream)
{
    const float* z  = (const float*)d_in[0];   // [65536, 256]
    const float* cb = (const float*)d_in[1];   // [1024, 256]

    float* out      = (float*)d_out;
    float* out_zq   = out;
    float* out_loss = out + (size_t)NROWS * D;
    float* out_idx  = out_loss + 1;

    char*   ws       = (char*)d_ws;
    short*  cb_swz   = (short*)ws;                       // 512 KB
    float*  c2       = (float*)(ws + 524288);            // 4 KB
    double* partials = (double*)(ws + 528384);           // 16 KB

    prep_kernel<<<132, 256, 0, stream>>>(cb, cb_swz, c2);
    vq_kernel<<<NBLK, 256, 0, stream>>>(z, cb, cb_swz, c2,
                                        out_zq, out_idx, partials);
    loss_kernel<<<1, 256, 0, stream>>>(partials, out_loss);
}

// Round 7
// 325.346 us; speedup vs baseline: 6.5962x; 1.0166x over previous
//
#include <hip/hip_runtime.h>
#include <hip/hip_bf16.h>

// VQ-VAE vector quantizer, MI355X — round 13.
// Rounds 7-12 post-mortem: six restructures of the screen all regressed; the
// r6 2-pass screen (true-min threshold -> tiny queue) is the verified optimum
// structure at 177us. r12's A/B showed the single-pass's loose threshold
// costs more in refine (6.8M bank conflicts) than pass 2 costs in MFMA/L2.
// Round 13 = exact r6 vq with three non-structural changes:
//   (1) ZS 264->260: refine's divergent-row ds_read_b128 stride becomes odd
//       in 16B units -> 8 bank-quad groups instead of 4 (2x -> 1x LDS cost).
//   (2) prep merged into one launch (swz float4 + c2; r12-verified values).
//   (3) loss_kernel fused via last-block finalize: partials + threadfence +
//       atomic counter; the last block re-runs the BIT-IDENTICAL loss tree
//       (same strided order) with device-scope atomic reads. prep zeroes the
//       counter each replay (stream-ordered before vq).
//
// d_out (float32): [0..16777215] z_q_st, [16777216] vq_loss, [+1..] indices.
// d_ws: [0,512K) cb_swz; [512K,+4K) c2; [528384,+16K) partials f64; [544768) ctr.

constexpr int D     = 256;
constexpr int NC    = 1024;
constexpr int NROWS = 65536;
constexpr int RPB   = 32;        // rows per block
constexpr int NBLK  = NROWS / RPB;   // 2048
constexpr int ZS    = 260;       // z_lds stride (floats): 65x16B, odd -> 8 groups
constexpr int QCAP  = 512;       // block-wide candidate queue capacity
#define MARGIN 3e-3f

typedef float accv4  __attribute__((ext_vector_type(4)));
typedef short short8 __attribute__((ext_vector_type(8)));

__device__ __forceinline__ short f2bf(float x) {
    __hip_bfloat16 h = __float2bfloat16(x);   // RNE (prep kernel only)
    return *reinterpret_cast<short*>(&h);
}
// pack truncated bf16(x) into low16, bf16(y) into high16 (2 VALU ops)
__device__ __forceinline__ unsigned packtrunc(float x, float y) {
    return (__float_as_uint(x) >> 16) | (__float_as_uint(y) & 0xffff0000u);
}

// numpy pairwise sum of x[0..127]^2 — 8-chain scheme (round-2 verified).
__device__ __forceinline__ float np_pairwise_sq128(const float* __restrict__ x) {
    float r[8];
    #pragma unroll
    for (int j = 0; j < 8; ++j) r[j] = __fmul_rn(x[j], x[j]);
    #pragma unroll
    for (int i = 8; i < 128; i += 8)
        #pragma unroll
        for (int j = 0; j < 8; ++j)
            r[j] = __fadd_rn(r[j], __fmul_rn(x[i + j], x[i + j]));
    float s01 = __fadd_rn(r[0], r[1]);
    float s23 = __fadd_rn(r[2], r[3]);
    float s45 = __fadd_rn(r[4], r[5]);
    float s67 = __fadd_rn(r[6], r[7]);
    return __fadd_rn(__fadd_rn(s01, s23), __fadd_rn(s45, s67));
}

// --- prep: swizzle (blocks 0..127, float4-vectorized) + c2 (blocks 128..131)
// swz: short8 element t = tile*512 + ks*64 + lane holds
//   cb[tile*16 + (lane&15)][ks*32 + (lane>>4)*8 + j],  j=0..7
__global__ void prep_kernel(const float* __restrict__ cb,
                            short* __restrict__ swz,
                            float* __restrict__ c2,
                            unsigned* __restrict__ ctr)
{
    int b = blockIdx.x;
    if (b < 128) {
        int t = b * 256 + threadIdx.x;   // 0..32767
        int lane = t & 63, ts = t >> 6;
        int ks = ts & 7, tile = ts >> 3;
        int code = tile * 16 + (lane & 15);
        int kb   = ks * 32 + (lane >> 4) * 8;
        const float* src = cb + (size_t)code * D + kb;
        float4 v0 = *(const float4*)(src);
        float4 v1 = *(const float4*)(src + 4);
        union { short s[8]; short8 v; } u;
        u.s[0] = f2bf(v0.x); u.s[1] = f2bf(v0.y);
        u.s[2] = f2bf(v0.z); u.s[3] = f2bf(v0.w);
        u.s[4] = f2bf(v1.x); u.s[5] = f2bf(v1.y);
        u.s[6] = f2bf(v1.z); u.s[7] = f2bf(v1.w);
        *((short8*)swz + t) = u.v;
    } else {
        if (b == 131 && threadIdx.x == 0) *ctr = 0u;   // replay-safe reset
        int t = (b - 128) * 256 + threadIdx.x;
        if (t < NC) {
            const float* x = cb + (size_t)t * D;
            c2[t] = __fadd_rn(np_pairwise_sq128(x), np_pairwise_sq128(x + 128));
        }
    }
}

// --- main: 2-pass screen + flat refine + epilogue + fused loss finalize -----
__global__ __launch_bounds__(256, 2) void vq_kernel(
    const float* __restrict__ z,
    const float* __restrict__ cb,
    const short* __restrict__ cb_swz,
    const float* __restrict__ c2g,
    float*       __restrict__ out_zq,
    float*       __restrict__ out_idx,
    double*      __restrict__ partials,
    float*       __restrict__ out_loss,
    unsigned*    __restrict__ ctr)
{
    __shared__ __align__(16) float z_lds[RPB][ZS];     // 33280 B
    __shared__ float a_row[RPB];
    __shared__ __align__(16) float scratchA[RPB][4];   // A_n tree; then best64
    __shared__ float c2_lds[NC];                        // 4096 B
    __shared__ int   rm_shared[RPB];                    // approx min; then winners
    __shared__ __align__(16) int queue[QCAP];           // 2048 B; then f64 scratch
    __shared__ int   qn;
    __shared__ int   amLast;

    const int tid     = threadIdx.x;
    const int lane    = tid & 63;
    const int w       = tid >> 6;         // wave 0..3
    const int rowBase = blockIdx.x * RPB;

    // ---- phase 1: stage z (fp32), c2, init ----
    #pragma unroll
    for (int j = 0; j < 8; ++j) {
        int l = tid + 256 * j;
        int row = l >> 6, q = l & 63;
        float4 v = *(const float4*)(z + (size_t)(rowBase + row) * D + q * 4);
        *(float4*)&z_lds[row][q * 4] = v;
    }
    #pragma unroll
    for (int j = 0; j < 4; ++j) c2_lds[tid + 256 * j] = c2g[tid + 256 * j];
    if (tid < RPB) rm_shared[tid] = 0x7f800000;   // +inf
    if (tid == 0)  qn = 0;
    __syncthreads();

    // ---- phase 2: A_n (numpy pairwise, round-2-exact tree), 4 threads/row ----
    if (tid < RPB * 4) {
        int row = tid >> 2, q = tid & 3;
        int h = (q >> 1) * 128, p = (q & 1) * 4;
        const float* x = &z_lds[row][0];
        float r0 = __fmul_rn(x[h+p+0], x[h+p+0]);
        float r1 = __fmul_rn(x[h+p+1], x[h+p+1]);
        float r2 = __fmul_rn(x[h+p+2], x[h+p+2]);
        float r3 = __fmul_rn(x[h+p+3], x[h+p+3]);
        #pragma unroll
        for (int i = 8; i < 128; i += 8) {
            r0 = __fadd_rn(r0, __fmul_rn(x[h+i+p+0], x[h+i+p+0]));
            r1 = __fadd_rn(r1, __fmul_rn(x[h+i+p+1], x[h+i+p+1]));
            r2 = __fadd_rn(r2, __fmul_rn(x[h+i+p+2], x[h+i+p+2]));
            r3 = __fadd_rn(r3, __fmul_rn(x[h+i+p+3], x[h+i+p+3]));
        }
        scratchA[row][q] = __fadd_rn(__fadd_rn(r0, r1), __fadd_rn(r2, r3));
    }
    __syncthreads();
    if (tid < RPB) {
        float half0 = __fadd_rn(scratchA[tid][0], scratchA[tid][1]);
        float half1 = __fadd_rn(scratchA[tid][2], scratchA[tid][3]);
        a_row[tid]  = __fadd_rn(half0, half1);
    }
    __syncthreads();

    // ---- phase 3: A-fragments from GLOBAL z (truncated bf16, no LDS) ----
    // lane L, row-tile rt, k-slice ks: rows rt*16+(L&15), dims ks*32+(L>>4)*8..+7
    short8 afrag[2][8];
    #pragma unroll
    for (int rt = 0; rt < 2; ++rt)
        #pragma unroll
        for (int ks = 0; ks < 8; ++ks) {
            const float* src = z + (size_t)(rowBase + rt * 16 + (lane & 15)) * D
                                 + ks * 32 + (lane >> 4) * 8;
            float4 v0 = *(const float4*)(src);
            float4 v1 = *(const float4*)(src + 4);
            union { unsigned u[4]; short8 v; } pk;
            pk.u[0] = packtrunc(v0.x, v0.y);
            pk.u[1] = packtrunc(v0.z, v0.w);
            pk.u[2] = packtrunc(v1.x, v1.y);
            pk.u[3] = packtrunc(v1.z, v1.w);
            afrag[rt][ks] = pk.v;
        }
    float a_reg[2][4];
    #pragma unroll
    for (int rt = 0; rt < 2; ++rt)
        #pragma unroll
        for (int i = 0; i < 4; ++i)
            a_reg[rt][i] = a_row[rt * 16 + (lane >> 4) * 4 + i];

    float runmin[2][4], thr[2][4];
    #pragma unroll
    for (int rt = 0; rt < 2; ++rt)
        #pragma unroll
        for (int i = 0; i < 4; ++i) runmin[rt][i] = 3.4e38f;

    // ---- phase 4: two-pass MFMA screen with B prefetch ----
    const short8* bbase = (const short8*)cb_swz + lane;
    for (int pass = 0; pass < 2; ++pass) {
        short8 bcur[8];
        #pragma unroll
        for (int ks = 0; ks < 8; ++ks) bcur[ks] = bbase[(size_t)w * 512 + ks * 64];
        for (int t = 0; t < 16; ++t) {
            int tile = w + 4 * t;
            short8 bnxt[8];
            if (t < 15) {
                int ntile = tile + 4;
                #pragma unroll
                for (int ks = 0; ks < 8; ++ks)
                    bnxt[ks] = bbase[(size_t)ntile * 512 + ks * 64];
            }
            accv4 acc[2];
            #pragma unroll
            for (int rt = 0; rt < 2; ++rt) acc[rt] = (accv4){0.f, 0.f, 0.f, 0.f};
            #pragma unroll
            for (int ks = 0; ks < 8; ++ks) {
                #pragma unroll
                for (int rt = 0; rt < 2; ++rt)
                    acc[rt] = __builtin_amdgcn_mfma_f32_16x16x32_bf16(
                        afrag[rt][ks], bcur[ks], acc[rt], 0, 0, 0);
            }
            int   col  = lane & 15;
            int   code = tile * 16 + col;
            float c2v  = c2_lds[code];
            #pragma unroll
            for (int rt = 0; rt < 2; ++rt)
                #pragma unroll
                for (int i = 0; i < 4; ++i) {
                    float key = (a_reg[rt][i] + c2v) - 2.0f * acc[rt][i];
                    if (pass == 0) {
                        runmin[rt][i] = fminf(runmin[rt][i], key);
                    } else if (key <= thr[rt][i]) {
                        int row  = rt * 16 + (lane >> 4) * 4 + i;
                        int slot = atomicAdd(&qn, 1);
                        if (slot < QCAP) queue[slot] = (row << 10) | code;
                    }
                }
            #pragma unroll
            for (int ks = 0; ks < 8; ++ks) bcur[ks] = bnxt[ks];
        }
        if (pass == 0) {
            #pragma unroll
            for (int rt = 0; rt < 2; ++rt)
                #pragma unroll
                for (int i = 0; i < 4; ++i) {
                    float m = runmin[rt][i];
                    m = fminf(m, __shfl_xor(m, 1));
                    m = fminf(m, __shfl_xor(m, 2));
                    m = fminf(m, __shfl_xor(m, 4));
                    m = fminf(m, __shfl_xor(m, 8));
                    if ((lane & 15) == 0) {
                        int row = rt * 16 + (lane >> 4) * 4 + i;
                        atomicMin(&rm_shared[row], __float_as_int(m));
                    }
                }
            __syncthreads();
            #pragma unroll
            for (int rt = 0; rt < 2; ++rt)
                #pragma unroll
                for (int i = 0; i < 4; ++i) {
                    int row = rt * 16 + (lane >> 4) * 4 + i;
                    thr[rt][i] = __int_as_float(rm_shared[row]) + MARGIN;
                }
        }
    }

    // ---- phase 5: exact refinement (bit-identical to round-2 keys) ----
    unsigned long long* best64 = (unsigned long long*)&scratchA[0][0];
    if (tid < RPB) best64[tid] = ~0ull;
    __syncthreads();
    int total = qn;
    if (total <= QCAP) {
        for (int t = tid; t < total; t += 256) {
            int e = queue[t];
            int row = e >> 10, code = e & 1023;
            const float4* cp = (const float4*)(cb + (size_t)code * D);
            const float*  zr = &z_lds[row][0];
            float acc = 0.0f;
            #pragma unroll 8
            for (int d4 = 0; d4 < 64; ++d4) {
                float4 cv = cp[d4];
                acc = fmaf(zr[d4 * 4 + 0], cv.x, acc);
                acc = fmaf(zr[d4 * 4 + 1], cv.y, acc);
                acc = fmaf(zr[d4 * 4 + 2], cv.z, acc);
                acc = fmaf(zr[d4 * 4 + 3], cv.w, acc);
            }
            float key = __fsub_rn(__fadd_rn(a_row[row], c2_lds[code]), 2.0f * acc);
            unsigned long long pk =
                ((unsigned long long)__float_as_uint(key) << 32) | (unsigned)code;
            atomicMin(&best64[row], pk);
        }
    } else {
        for (int r = 0; r < RPB; ++r) {
            for (int c = tid; c < NC; c += 256) {
                const float4* cp = (const float4*)(cb + (size_t)c * D);
                const float*  zr = &z_lds[r][0];
                float acc = 0.0f;
                #pragma unroll 8
                for (int d4 = 0; d4 < 64; ++d4) {
                    float4 cv = cp[d4];
                    acc = fmaf(zr[d4 * 4 + 0], cv.x, acc);
                    acc = fmaf(zr[d4 * 4 + 1], cv.y, acc);
                    acc = fmaf(zr[d4 * 4 + 2], cv.z, acc);
                    acc = fmaf(zr[d4 * 4 + 3], cv.w, acc);
                }
                float key = __fsub_rn(__fadd_rn(a_row[r], c2_lds[c]), 2.0f * acc);
                unsigned long long pk =
                    ((unsigned long long)__float_as_uint(key) << 32) | (unsigned)c;
                atomicMin(&best64[r], pk);
            }
        }
    }
    __syncthreads();

    // ---- phase 6: winners ----
    int* winner = rm_shared;   // reuse
    if (tid < RPB) {
        unsigned long long b = best64[tid];
        int wdx = (b == ~0ull) ? 0 : (int)(b & 0xffffffffu);
        winner[tid] = wdx;
        out_idx[rowBase + tid] = (float)wdx;
    }
    __syncthreads();

    // ---- phase 7: vectorized epilogue (float4 path, wave-uniform row) ----
    double lacc = 0.0;
    #pragma unroll
    for (int j = 0; j < 8; ++j) {
        int idx = tid + 256 * j;      // 0..2047
        int row = idx >> 6;           // wave-uniform
        int q4  = idx & 63;
        int wd  = winner[row];
        float4 cv = *(const float4*)(cb + (size_t)wd * D + q4 * 4);
        float4 zv = *(const float4*)&z_lds[row][q4 * 4];
        float4 o;
        o.x = __fadd_rn(zv.x, __fsub_rn(cv.x, zv.x));
        o.y = __fadd_rn(zv.y, __fsub_rn(cv.y, zv.y));
        o.z = __fadd_rn(zv.z, __fsub_rn(cv.z, zv.z));
        o.w = __fadd_rn(zv.w, __fsub_rn(cv.w, zv.w));
        *(float4*)(out_zq + (size_t)(rowBase + row) * D + q4 * 4) = o;
        double d0 = (double)zv.x - (double)cv.x;
        double d1 = (double)zv.y - (double)cv.y;
        double d2 = (double)zv.z - (double)cv.z;
        double d3 = (double)zv.w - (double)cv.w;
        lacc += d0 * d0 + d1 * d1 + d2 * d2 + d3 * d3;
    }
    __syncthreads();
    double* dred = (double*)&queue[0];   // 512 ints = 256 doubles
    dred[tid] = lacc;
    __syncthreads();
    for (int s = 128; s > 0; s >>= 1) {
        if (tid < s) dred[tid] += dred[tid + s];
        __syncthreads();
    }

    // ---- phase 8: fused loss finalize (last-block idiom, bit-exact tree) ----
    if (tid == 0) {
        partials[blockIdx.x] = dred[0];
        __threadfence();                        // release partials to device
        unsigned old = atomicAdd(ctr, 1u);
        amLast = (old == (unsigned)(NBLK - 1)) ? 1 : 0;
    }
    __syncthreads();
    if (amLast) {
        __threadfence();                        // acquire
        double s = 0.0;
        for (int i = tid; i < NBLK; i += 256)   // same order as loss_kernel
            s += atomicAdd(&partials[i], 0.0);  // device-scope fresh read
        dred[tid] = s;
        __syncthreads();
        for (int k = 128; k > 0; k >>= 1) {
            if (tid < k) dred[tid] += dred[tid + k];
            __syncthreads();
        }
        if (tid == 0)
            out_loss[0] = (float)(1.25 * dred[0] / (double)((size_t)NROWS * D));
    }
}

extern "C" void kernel_launch(void* const* d_in, const int* in_sizes, int n_in,
                              void* d_out, int out_size, void* d_ws, size_t ws_size,
                              hipStream_t stream)
{
    const float* z  = (const float*)d_in[0];   // [65536, 256]
    const float* cb = (const float*)d_in[1];   // [1024, 256]

    float* out      = (float*)d_out;
    float* out_zq   = out;
    float* out_loss = out + (size_t)NROWS * D;
    float* out_idx  = out_loss + 1;

    char*     ws       = (char*)d_ws;
    short*    cb_swz   = (short*)ws;                     // 512 KB
    float*    c2       = (float*)(ws + 524288);          // 4 KB
    double*   partials = (double*)(ws + 528384);         // 16 KB
    unsigned* ctr      = (unsigned*)(ws + 544768);       // 4 B

    prep_kernel<<<132, 256, 0, stream>>>(cb, cb_swz, c2, ctr);
    vq_kernel<<<NBLK, 256, 0, stream>>>(z, cb, cb_swz, c2,
                                        out_zq, out_idx, partials,
                                        out_loss, ctr);
}